// Round 1
// baseline (394.109 us; speedup 1.0000x reference)
//
#include <hip/hip_runtime.h>
#include <math.h>
#include <stdint.h>

// Problem shape (fixed by setup_inputs): P=512, R=256, S=256, K=3, threshold=0.
#define Pn 512
#define Rn 256
#define Sn 256

typedef unsigned long long u64;
typedef unsigned int u32;

// ---- u64 key machinery (proven in prior rounds): larger key == larger value,
// ties broken toward smaller index (lax.top_k semantics). ----
__device__ __forceinline__ u32 mono(float f) {
  u32 u = __float_as_uint(f);
  return (u & 0x80000000u) ? ~u : (u | 0x80000000u);
}
__device__ __forceinline__ float unmono(u32 m) {
  u32 bits = (m & 0x80000000u) ? (m & 0x7FFFFFFFu) : ~m;
  return __uint_as_float(bits);
}
__device__ __forceinline__ u64 makekey(float v, int idx) {
  return ((u64)mono(v) << 32) | (u32)(~(u32)idx);
}
__device__ __forceinline__ int key_idx(u64 k) { return (int)(~(u32)k); }
__device__ __forceinline__ float key_val(u64 k) { return unmono((u32)(k >> 32)); }

// ---- branchless float top-3 insert (proven). Strict >, ascending visit
// order => smaller index wins ties = lax.top_k semantics. ----
__device__ __forceinline__ void ins3f(float v, int i,
    float& t0, int& i0, float& t1, int& i1, float& t2, int& i2) {
  const bool b0 = v > t0, b1 = v > t1, b2 = v > t2;
  const float nt0 = b0 ? v : t0;
  const int   ni0 = b0 ? i : i0;
  const float nt1 = b0 ? t0 : (b1 ? v : t1);
  const int   ni1 = b0 ? i0 : (b1 ? i : i1);
  const float nt2 = b1 ? t1 : (b2 ? v : t2);
  const int   ni2 = b1 ? i1 : (b2 ? i : i2);
  t0 = nt0; i0 = ni0; t1 = nt1; i1 = ni1; t2 = nt2; i2 = ni2;
}

// branchless key top-3 insert (total order on u64 keys).
__device__ __forceinline__ void ins3k(u64 k, u64& k0, u64& k1, u64& k2) {
  const bool b0 = k > k0, b1 = k > k1, b2 = k > k2;
  const u64 n0 = b0 ? k : k0;
  const u64 n1 = b0 ? k0 : (b1 ? k : k1);
  const u64 n2 = b1 ? k1 : (b2 ? k : k2);
  k0 = n0; k1 = n1; k2 = n2;
}

#define CHUNK 32
#define TSTRIDE 257  // 32x257 f32 tile: odd stride -> all patterns <=2-way bank alias (free)

// K1: one block per p. Single full read of the input.
//  - thread-per-column serial scan over all 256 rows -> COMPLETE col top-3
//    (3 planes, no cross-block merge needed anymore).
//  - rows staged through LDS in 32-row chunks; 8 threads/row scan 32 cols each
//    from LDS, per-row merge via small LDS key exchange -> row top-3 keys.
// Replaces the old 12-plane col partials AND the K2 butterfly + score re-read.
__global__ __launch_bounds__(256) void tops_kernel(
    const float* __restrict__ score,
    float* __restrict__ colv, int* __restrict__ coli,
    u64* __restrict__ rowk) {
  __shared__ float tile[CHUNK * TSTRIDE];   // 32,896 B
  __shared__ u64   pk[8 * CHUNK * 3];       //  6,144 B  (8 quarters x 32 rows x 3)
  const int p  = blockIdx.x;
  const int s  = threadIdx.x;        // column 0..255
  const int rr = threadIdx.x & 31;   // row-in-chunk for the row scan
  const int q  = threadIdx.x >> 5;   // 8 col-quarters of 32
  const float* base = score + (size_t)p * (Rn * Sn) + s;

  float t0 = -INFINITY, t1 = -INFINITY, t2 = -INFINITY;
  int   i0 = -1, i1 = -1, i2 = -1;

  for (int c = 0; c < 8; ++c) {
    const int r0 = c * CHUNK;
    // Stage chunk + column scan. Wave access per row = 256B contiguous
    // (coalesced); LDS writes lane-consecutive (conflict-free).
    #pragma unroll 16
    for (int r = 0; r < CHUNK; ++r) {
      const float v = base[(size_t)(r0 + r) * Sn];
      tile[r * TSTRIDE + s] = v;
      ins3f(v, r0 + r, t0, i0, t1, i1, t2, i2);
    }
    __syncthreads();
    // Row scan: thread (rr,q) scans cols q*32..q*32+31 of row r0+rr.
    // LDS read addr = rr*257 + cb + j: odd stride -> 2-way alias = free.
    u64 k0 = 0, k1 = 0, k2 = 0;
    const int cb = q * 32;
    #pragma unroll 8
    for (int j = 0; j < 32; ++j)
      ins3k(makekey(tile[rr * TSTRIDE + cb + j], cb + j), k0, k1, k2);
    pk[(q * CHUNK + rr) * 3 + 0] = k0;
    pk[(q * CHUNK + rr) * 3 + 1] = k1;
    pk[(q * CHUNK + rr) * 3 + 2] = k2;
    __syncthreads();
    // Merge the 8 quarter-partials per row; threads 0..31 (one per row).
    if (threadIdx.x < 32) {
      u64 m0 = pk[threadIdx.x * 3 + 0];
      u64 m1 = pk[threadIdx.x * 3 + 1];
      u64 m2 = pk[threadIdx.x * 3 + 2];
      #pragma unroll
      for (int qq = 1; qq < 8; ++qq) {
        #pragma unroll
        for (int kk = 0; kk < 3; ++kk)
          ins3k(pk[(qq * CHUNK + threadIdx.x) * 3 + kk], m0, m1, m2);
      }
      const size_t ro = ((size_t)p * Rn + r0 + threadIdx.x) * 3;
      rowk[ro + 0] = m0; rowk[ro + 1] = m1; rowk[ro + 2] = m2;
    }
    __syncthreads();  // pk/tile safe to overwrite next chunk
  }
  // Complete col top-3: 3 planes, coalesced.
  const size_t PS = (size_t)Pn * Sn;
  const size_t o  = (size_t)p * Sn + s;
  colv[0 * PS + o] = t0; coli[0 * PS + o] = i0;
  colv[1 * PS + o] = t1; coli[1 * PS + o] = i1;
  colv[2 * PS + o] = t2; coli[2 * PS + o] = i2;
}

__device__ __forceinline__ void compute_elem(
    int s, int r, bool rmask, int sm,
    float rv0, float rv1, float rv2, int ri0, int ri1, int ri2,
    float a0, int b0, float a1, int b1, float a2, int b2,
    float& oscore, float& ocorr) {
  const float rv = (s == ri0) ? rv0 : (s == ri1) ? rv1 : (s == ri2) ? rv2 : 0.0f;
  const float sv = (r == b0) ? a0 : (r == b1) ? a1 : (r == b2) ? a2 : 0.0f;
  oscore = 0.5f * (rv + sv);
  const bool m = rmask && (sm != 0);
  ocorr = (((rv > 0.0f) || (sv > 0.0f)) && m) ? 1.0f : 0.0f;
}

// K2: pure streaming-write kernel. Reads only the tiny tops (3 col planes +
// 3 row keys/row, wave-uniform broadcast) — no score re-read, no shuffles,
// no LDS. Per (p, 64-row slab) block; warp per row; float4 stores.
__global__ __launch_bounds__(256) void write_kernel(
    const float* __restrict__ colv, const int* __restrict__ coli,
    const u64* __restrict__ rowk,
    const int* __restrict__ rmaskp, const int* __restrict__ smaskp,
    float* __restrict__ out) {
  const int p     = blockIdx.x >> 2;
  const int rbase = (blockIdx.x & 3) * 64;
  const int warp  = threadIdx.x >> 6;
  const int lane  = threadIdx.x & 63;
  const size_t PS = (size_t)Pn * Sn;
  const size_t N  = (size_t)Pn * Rn * Sn;
  const size_t cb = (size_t)p * Sn;

  // Each warp holds the full col top-3 (4 cols/lane), already complete.
  float4 T0 = reinterpret_cast<const float4*>(colv + 0 * PS + cb)[lane];
  float4 T1 = reinterpret_cast<const float4*>(colv + 1 * PS + cb)[lane];
  float4 T2 = reinterpret_cast<const float4*>(colv + 2 * PS + cb)[lane];
  int4   I0 = reinterpret_cast<const int4*>(coli + 0 * PS + cb)[lane];
  int4   I1 = reinterpret_cast<const int4*>(coli + 1 * PS + cb)[lane];
  int4   I2 = reinterpret_cast<const int4*>(coli + 2 * PS + cb)[lane];
  T0.x = expf(T0.x); T0.y = expf(T0.y); T0.z = expf(T0.z); T0.w = expf(T0.w);
  T1.x = expf(T1.x); T1.y = expf(T1.y); T1.z = expf(T1.z); T1.w = expf(T1.w);
  T2.x = expf(T2.x); T2.y = expf(T2.y); T2.z = expf(T2.z); T2.w = expf(T2.w);

  const int4 sm = reinterpret_cast<const int4*>(smaskp + cb)[lane];
  const int sbase = lane * 4;
  float* outp = out + (size_t)p * (Rn * Sn);

  #pragma unroll 4
  for (int it = 0; it < 16; ++it) {
    const int r = rbase + it * 4 + warp;
    // Row top-3: 3 wave-uniform u64 loads (L2-hot broadcast), decode + exp.
    const size_t ro = ((size_t)p * Rn + r) * 3;
    const u64 rk0 = rowk[ro + 0];
    const u64 rk1 = rowk[ro + 1];
    const u64 rk2 = rowk[ro + 2];
    const float rv0 = expf(key_val(rk0));
    const float rv1 = expf(key_val(rk1));
    const float rv2 = expf(key_val(rk2));
    const int   ri0 = key_idx(rk0), ri1 = key_idx(rk1), ri2 = key_idx(rk2);
    const bool  rm  = rmaskp[p * Rn + r] != 0;   // wave-uniform scalar load

    float4 osc, oco;
    compute_elem(sbase + 0, r, rm, sm.x, rv0, rv1, rv2, ri0, ri1, ri2,
                 T0.x, I0.x, T1.x, I1.x, T2.x, I2.x, osc.x, oco.x);
    compute_elem(sbase + 1, r, rm, sm.y, rv0, rv1, rv2, ri0, ri1, ri2,
                 T0.y, I0.y, T1.y, I1.y, T2.y, I2.y, osc.y, oco.y);
    compute_elem(sbase + 2, r, rm, sm.z, rv0, rv1, rv2, ri0, ri1, ri2,
                 T0.z, I0.z, T1.z, I1.z, T2.z, I2.z, osc.z, oco.z);
    compute_elem(sbase + 3, r, rm, sm.w, rv0, rv1, rv2, ri0, ri1, ri2,
                 T0.w, I0.w, T1.w, I1.w, T2.w, I2.w, osc.w, oco.w);

    reinterpret_cast<float4*>(outp + (size_t)r * Sn)[lane]     = osc;
    reinterpret_cast<float4*>(outp + N + (size_t)r * Sn)[lane] = oco;
  }
}

extern "C" void kernel_launch(void* const* d_in, const int* in_sizes, int n_in,
                              void* d_out, int out_size, void* d_ws, size_t ws_size,
                              hipStream_t stream) {
  const float* score = (const float*)d_in[0];
  // d_in[1] = node_corr_scores: unused (conditional=False in reference)
  const int* rmask = (const int*)d_in[2];
  const int* smask = (const int*)d_in[3];
  float* out = (float*)d_out;

  const size_t PS = (size_t)Pn * Sn;
  // Workspace: 3 complete col planes (v+i) + row top-3 keys. 6 MiB total
  // (was 12 MiB) — fits the previously-verified workspace budget.
  float* colv = (float*)d_ws;                      // 3*PS floats
  int*   coli = (int*)(colv + 3 * PS);             // 3*PS ints
  u64*   rowk = (u64*)(coli + 3 * PS);             // Pn*Rn*3 keys

  tops_kernel<<<Pn, 256, 0, stream>>>(score, colv, coli, rowk);
  write_kernel<<<Pn * 4, 256, 0, stream>>>(colv, coli, rowk,
                                           rmask, smask, out);
}